// Round 14
// baseline (128.330 us; speedup 1.0000x reference)
//
#include <hip/hip_runtime.h>
#include <math.h>

#define RESQ 7
#define CH   256
#define NROI 512
#define BC   128
#define NB   3
#define NT   512

typedef __bf16 bh8  __attribute__((ext_vector_type(8)));
typedef float  f16v __attribute__((ext_vector_type(16)));

// LDS-only barrier: drain LDS counter, NOT vmcnt -> global prefetch stays in flight
#define BAR() do { \
    asm volatile("s_waitcnt lgkmcnt(0)" ::: "memory"); \
    __builtin_amdgcn_s_barrier(); \
    asm volatile("" ::: "memory"); \
} while (0)

// ---- d_ws layout (bytes): fragment-major A panels ----
#define A1OFF 0            // [3 ib][4 mt][16 t][64 lane][8] bf16 = 196608
#define A2OFF 196608       // [3][9 tap][4 mt][8 t][64][8]       = 884736
#define A3OFF 1081344      // [3][8 mt][8 t][64][8]              = 196608
#define ATOFF 1277952      // [4 quad][8 mt][16 t][64][8]        = 524288
#define WS_BYTES 1802240
#define FTOFF 1802240      // feat_t [16][36][36][256] bf16 -> 10616832 B
#define WS_FULL 12419072
#define PRE_ELEMS 901120

// ---- LDS (bytes) ----
#define XS_OFF 0           // xs [49 sp][256 ch] bf16, stride 512
#define T1_OFF 25088       // t1 [81 rows][128 ch] bf16, stride 256
#define T2_OFF 45824       // t2 [49 sp][128 ch] bf16, stride 256
#define WY_OFF 58368       // 252 f32
#define WX_OFF 59376       // 252 f32
#define LG_OFF 60384       // logits [4 quad][4 mg][64] f32 = 4096
#define LDS_BYTES 64480

#define SWZ(row) (((row) & 15) << 4)

__device__ __forceinline__ float Fk(float t) {
    t = fminf(1.f, fmaxf(-1.f, t));
    float a = t + 1.f, b = 1.f - t;
    return (t < 0.f) ? 0.5f * a * a : 1.f - 0.5f * b * b;
}
__device__ __forceinline__ unsigned short bf16bits(float a) {
    return __builtin_bit_cast(unsigned short, (__bf16)a);
}
__device__ __forceinline__ unsigned int pk2(float a, float b) {
    return (unsigned int)bf16bits(a) | ((unsigned int)bf16bits(b) << 16);
}
__device__ __forceinline__ float b2f(unsigned int s) {
    return __builtin_bit_cast(float, s << 16);
}
__device__ __forceinline__ bh8 ld_bh8(const unsigned char* p) { return *(const bh8*)p; }
__device__ __forceinline__ bh8 cvt8(const float* p) {
    float4 a = *(const float4*)p;
    float4 b = *(const float4*)(p + 4);
    bh8 r;
    r[0]=(__bf16)a.x; r[1]=(__bf16)a.y; r[2]=(__bf16)a.z; r[3]=(__bf16)a.w;
    r[4]=(__bf16)b.x; r[5]=(__bf16)b.y; r[6]=(__bf16)b.z; r[7]=(__bf16)b.w;
    return r;
}
__device__ __forceinline__ bh8 gather8(const float* p, int stride) {
    bh8 r;
    #pragma unroll
    for (int j = 0; j < 8; ++j) r[j] = (__bf16)p[j * stride];
    return r;
}

// epilogue helpers (compile-time reg indices only)
__device__ __forceinline__ void epi_store(const f16v acc, int chbase, int h,
        const float* sarr, const float* barr, unsigned char* rowbase, int rswz) {
    #pragma unroll
    for (int g = 0; g < 4; ++g) {
        const int ch = chbase + 8*g + 4*h;
        const float4 sv = *(const float4*)(sarr + ch);
        const float4 bv = *(const float4*)(barr + ch);
        float v0 = fmaxf(fmaf(acc[4*g+0], sv.x, bv.x), 0.f);
        float v1 = fmaxf(fmaf(acc[4*g+1], sv.y, bv.y), 0.f);
        float v2 = fmaxf(fmaf(acc[4*g+2], sv.z, bv.z), 0.f);
        float v3 = fmaxf(fmaf(acc[4*g+3], sv.w, bv.w), 0.f);
        *(uint2*)(rowbase + ((2*ch) ^ rswz)) = make_uint2(pk2(v0,v1), pk2(v2,v3));
    }
}
__device__ __forceinline__ void epi_res(const f16v acc, int chbase, int h,
        const float* sarr, const float* barr, unsigned char* rowbase, int rswz) {
    #pragma unroll
    for (int g = 0; g < 4; ++g) {
        const int ch = chbase + 8*g + 4*h;
        const float4 sv = *(const float4*)(sarr + ch);
        const float4 bv = *(const float4*)(barr + ch);
        unsigned char* p = rowbase + ((2*ch) ^ rswz);
        const uint2 old = *(const uint2*)p;
        float v0 = fmaxf(fmaf(acc[4*g+0], sv.x, bv.x) + b2f(old.x & 0xFFFFu), 0.f);
        float v1 = fmaxf(fmaf(acc[4*g+1], sv.y, bv.y) + b2f(old.x >> 16), 0.f);
        float v2 = fmaxf(fmaf(acc[4*g+2], sv.z, bv.z) + b2f(old.y & 0xFFFFu), 0.f);
        float v3 = fmaxf(fmaf(acc[4*g+3], sv.w, bv.w) + b2f(old.y >> 16), 0.f);
        *(uint2*)p = make_uint2(pk2(v0,v1), pk2(v2,v3));
    }
}
__device__ __forceinline__ float dq_part(const f16v acc, int chbase, int h,
        const float* bt, const float* wm) {
    float part = 0.f;
    #pragma unroll
    for (int g = 0; g < 4; ++g) {
        const int ch = chbase + 8*g + 4*h;
        const float4 btv = *(const float4*)(bt + ch);
        const float4 wmv = *(const float4*)(wm + ch);
        part = fmaf(wmv.x, fmaxf(acc[4*g+0] + btv.x, 0.f), part);
        part = fmaf(wmv.y, fmaxf(acc[4*g+1] + btv.y, 0.f), part);
        part = fmaf(wmv.z, fmaxf(acc[4*g+2] + btv.z, 0.f), part);
        part = fmaf(wmv.w, fmaxf(acc[4*g+3] + btv.w, 0.f), part);
    }
    return part;
}

// ---------------- prepass: fragment-major weights + feat transpose ----------------
extern "C" __global__ void prep_all(const float* __restrict__ feat,
                                    const float* __restrict__ w1,
                                    const float* __restrict__ w2,
                                    const float* __restrict__ w3,
                                    const float* __restrict__ wt,
                                    unsigned char* __restrict__ ws,
                                    int do_ft) {
    __shared__ unsigned short tile[36 * 256];
    if (do_ft && blockIdx.x < 576) {
        const int b = blockIdx.x / 36, y = blockIdx.x % 36;
        const int c = threadIdx.x;  // 256 threads
        const float* src = feat + (size_t)(b * 256 + c) * 1296 + y * 36;
        float4 fv[9];
        #pragma unroll
        for (int i = 0; i < 9; ++i) fv[i] = *(const float4*)(src + i * 4);
        #pragma unroll
        for (int i = 0; i < 9; ++i) {
            tile[(i*4+0)*256 + c] = bf16bits(fv[i].x);
            tile[(i*4+1)*256 + c] = bf16bits(fv[i].y);
            tile[(i*4+2)*256 + c] = bf16bits(fv[i].z);
            tile[(i*4+3)*256 + c] = bf16bits(fv[i].w);
        }
        __syncthreads();
        unsigned short* dst = (unsigned short*)(ws + FTOFF) + (size_t)(b*36 + y)*36*256;
        for (int x = 0; x < 36; ++x) dst[x*256 + c] = tile[x*256 + c];
        return;
    }
    const int base = do_ft ? 576 : 0;
    const int nb = gridDim.x - base;
    __bf16* wb = (__bf16*)ws;
    for (int i = (blockIdx.x - base) * blockDim.x + threadIdx.x; i < PRE_ELEMS;
         i += nb * blockDim.x) {
        float v; int dst;
        if (i < 98304) {                       // A1 frag
            int e = i;
            int j = e & 7, lane = (e>>3)&63, t = (e>>9)&15, mt = (e>>13)&3, ib = e>>15;
            int m = mt*32 + (lane&31), k = t*16 + 8*(lane>>5) + j;
            v = w1[(ib*BC + m)*CH + k];
            dst = (A1OFF>>1) + e;
        } else if (i < 98304 + 442368) {       // A2 frag (tap-major)
            int e = i - 98304;
            int j = e & 7, lane = (e>>3)&63, t = (e>>9)&7, mt = (e>>12)&3;
            int rem = e >> 14;                 // ib*9 + tap
            int ib = rem / 9, tap = rem - ib*9;
            int m = mt*32 + (lane&31), ci = t*16 + 8*(lane>>5) + j;
            v = w2[((ib*BC + m)*BC + ci)*9 + tap];
            dst = (A2OFF>>1) + e;
        } else if (i < 98304 + 442368 + 98304) { // A3 frag
            int e = i - (98304 + 442368);
            int j = e & 7, lane = (e>>3)&63, t = (e>>9)&7, mt = (e>>12)&7, ib = e>>15;
            int m = mt*32 + (lane&31), ci = t*16 + 8*(lane>>5) + j;
            v = w3[(ib*CH + m)*BC + ci];
            dst = (A3OFF>>1) + e;
        } else {                                // AT frag
            int e = i - (98304 + 442368 + 98304);
            int j = e & 7, lane = (e>>3)&63, t = (e>>9)&15, mt = (e>>13)&7, quad = e>>16;
            int co = mt*32 + (lane&31), ci = t*16 + 8*(lane>>5) + j;
            v = wt[ci*1024 + co*4 + quad];
            dst = (ATOFF>>1) + e;
        }
        wb[dst] = (__bf16)v;
    }
}

// ---------------- fused main kernel ----------------
template<int USE_WS, int USE_FT>
__global__ __launch_bounds__(NT, 2)
void masknet_mfma(const float* __restrict__ feat,
                  const float* __restrict__ bbox,
                  const float* __restrict__ w1, const float* __restrict__ s1, const float* __restrict__ b1,
                  const float* __restrict__ w2, const float* __restrict__ s2, const float* __restrict__ b2,
                  const float* __restrict__ w3, const float* __restrict__ s3, const float* __restrict__ b3,
                  const float* __restrict__ wt, const float* __restrict__ bt,
                  const float* __restrict__ wm, const float* __restrict__ bm,
                  const unsigned char* __restrict__ ws,
                  float* __restrict__ out)
{
    __shared__ __align__(16) unsigned char smem[LDS_BYTES];
    float* wyb = (float*)(smem + WY_OFF);
    float* wxb = (float*)(smem + WX_OFF);
    float* lgf = (float*)(smem + LG_OFF);

    const int tid  = threadIdx.x;
    const int r    = blockIdx.x;
    const int bfr  = r >> 5;
    const int lane = tid & 63;
    const int ln   = lane & 31;
    const int h    = lane >> 5;
    const int w_   = tid >> 6;
    const int cb   = 16 * h;

    // ---- ROI params ----
    const float S = 1.f / 16.f;
    const float bx = bbox[r*4+0], by = bbox[r*4+1];
    const float bw_ = bbox[r*4+2], bh_ = bbox[r*4+3];
    const float x1 = bx * S, y1 = by * S;
    const float bwx = (bw_ * S) * (1.f / RESQ);
    const float bwy = (bh_ * S) * (1.f / RESQ);
    const float area = bwx * bwy;
    const float inv_area = (area > 0.f) ? 1.f / fmaxf(area, 1e-12f) : 0.f;

    // ---- Phase A: tables + zero t1 + zero logits ----
    if (tid < 252) {
        int p = tid / 36, i = tid - p * 36;
        float st = y1 + bwy * p, en = st + bwy;
        wyb[tid] = Fk(en - (float)i) - Fk(st - (float)i);
    } else if (tid >= 256 && tid < 508) {
        int t = tid - 256;
        int q = t / 36, i = t - q * 36;
        float st = x1 + bwx * q, en = st + bwx;
        wxb[t] = Fk(en - (float)i) - Fk(st - (float)i);
    }
    {
        uint4* z = (uint4*)(smem + T1_OFF);
        for (int o = tid; o < 1296; o += NT) z[o] = make_uint4(0,0,0,0);
        for (int o = tid; o < 1024; o += NT) lgf[o] = 0.f;
    }
    BAR();

    // ---- Phase B: PrRoI pool -> xs[s][c] bf16 (swizzled) ----
    if (USE_FT) {
        // 16 groups (wave-half per bin), lane = 8 channels, static 4x4 taps
        const unsigned short* ft = (const unsigned short*)(ws + FTOFF) + (size_t)bfr * (1296 * 256);
        const int g = w_ * 2 + h;   // 0..15
        #pragma unroll 1
        for (int k = 0; k < 4; ++k) {
            const int s = g + 16 * k;
            if (s >= 49) break;
            const int p = s / 7, q = s - p * 7;
            const float sy = y1 + bwy * p, sx = x1 + bwx * q;
            const int ylo = max(0, (int)floorf(sy)), yhi = min(35, (int)ceilf(sy + bwy));
            const int xlo = max(0, (int)floorf(sx)), xhi = min(35, (int)ceilf(sx + bwx));
            float wyv[4], wxv[4];
            #pragma unroll
            for (int j = 0; j < 4; ++j) {
                const int y = ylo + j, x = xlo + j;
                wyv[j] = (y <= yhi) ? wyb[p*36 + y] * inv_area : 0.f;
                wxv[j] = (x <= xhi) ? wxb[q*36 + x] : 0.f;
            }
            float ac0=0.f,ac1=0.f,ac2=0.f,ac3=0.f,ac4=0.f,ac5=0.f,ac6=0.f,ac7=0.f;
            #pragma unroll
            for (int yy = 0; yy < 4; ++yy) {
                const int y = min(ylo + yy, 35);
                const unsigned short* rowp = ft + (size_t)(y * 36) * 256 + ln * 8;
                #pragma unroll
                for (int xx = 0; xx < 4; ++xx) {
                    const int x = min(xlo + xx, 35);
                    const float wgt = wyv[yy] * wxv[xx];
                    const uint4 v = *(const uint4*)(rowp + x * 256);
                    ac0 = fmaf(wgt, b2f(v.x & 0xFFFFu), ac0);
                    ac1 = fmaf(wgt, b2f(v.x >> 16),     ac1);
                    ac2 = fmaf(wgt, b2f(v.y & 0xFFFFu), ac2);
                    ac3 = fmaf(wgt, b2f(v.y >> 16),     ac3);
                    ac4 = fmaf(wgt, b2f(v.z & 0xFFFFu), ac4);
                    ac5 = fmaf(wgt, b2f(v.z >> 16),     ac5);
                    ac6 = fmaf(wgt, b2f(v.w & 0xFFFFu), ac6);
                    ac7 = fmaf(wgt, b2f(v.w >> 16),     ac7);
                }
            }
            *(uint4*)(smem + XS_OFF + s * 512 + ((16 * ln) ^ SWZ(s))) =
                make_uint4(pk2(ac0,ac1), pk2(ac2,ac3), pk2(ac4,ac5), pk2(ac6,ac7));
        }
    } else {
        const float* fb = feat + (size_t)bfr * CH * 36 * 36;
        for (int o = tid; o < CH * 49; o += NT) {
            int c = o / 49, s = o - c * 49;
            int p = s / 7, q = s - p * 7;
            float sy = y1 + bwy * p, sx = x1 + bwx * q;
            int ylo = max(0, (int)floorf(sy)), yhi = min(35, (int)ceilf(sy + bwy));
            int xlo = max(0, (int)floorf(sx)), xhi = min(35, (int)ceilf(sx + bwx));
            const float* fc = fb + c * 1296;
            float acc = 0.f;
            for (int y = ylo; y <= yhi; ++y) {
                float wyv = wyb[p * 36 + y];
                for (int x = xlo; x <= xhi; ++x)
                    acc = fmaf(wyv * wxb[q * 36 + x], fc[y * 36 + x], acc);
            }
            *(unsigned short*)(smem + XS_OFF + s * 512 + ((2 * c) ^ SWZ(s))) =
                bf16bits(acc * inv_area);
        }
    }

    // wave geometry
    const int mt12 = w_ & 3, nt12 = w_ >> 2;           // conv1/2: 4m x 2n
    const int col12 = nt12 * 32 + ln;
    const int ncl12 = min(col12, 48);
    const int mg = w_ >> 1, ng = w_ & 1;               // conv3/deconv: (2 mt) x 2n
    const int col3 = ng * 32 + ln;
    const int ncl3 = min(col3, 48);

    // prefetch registers: first 4 A-frags of the upcoming phase, issued pre-barrier
    bh8 pf[4] = {};
    if (USE_WS) {
        #pragma unroll
        for (int t = 0; t < 4; ++t)
            pf[t] = ld_bh8(ws + A1OFF + ((((0*4 + mt12)*16 + t)*64 + lane) << 4));
    }
    BAR();

    // ---- Phase C: bottleneck blocks ----
    #pragma unroll 1
    for (int ib = 0; ib < NB; ++ib) {
        // ===== conv1: xs(256) -> t1(128 interior), K=256, 32x32 =====
        {
            const unsigned char* bb = smem + XS_OFF + ncl12 * 512;
            const int bswz = SWZ(ncl12);
            f16v acc = {};
            #pragma unroll
            for (int t = 0; t < 16; ++t) {
                bh8 a;
                if (USE_WS) a = (t < 4) ? pf[t]
                                        : ld_bh8(ws + A1OFF + ((((ib*4 + mt12)*16 + t)*64 + lane) << 4));
                else        a = cvt8(w1 + (size_t)(ib*BC + mt12*32 + ln)*CH + t*16 + 8*h);
                bh8 b = ld_bh8(bb + ((t*32 + cb) ^ bswz));
                acc = __builtin_amdgcn_mfma_f32_32x32x16_bf16(a, b, acc, 0, 0, 0);
            }
            if (col12 < 49) {
                const int row = (col12/7 + 1)*9 + (col12 - (col12/7)*7) + 1;
                epi_store(acc, mt12*32, h, s1 + ib*BC, b1 + ib*BC,
                          smem + T1_OFF + row*256, SWZ(row));
            }
        }
        if (USE_WS) {   // prefetch conv2 tap0 t=0..3
            #pragma unroll
            for (int t = 0; t < 4; ++t)
                pf[t] = ld_bh8(ws + A2OFF + (((((ib*9+0)*4 + mt12)*8 + t)*64 + lane) << 4));
        }
        BAR();

        // ===== conv2: 3x3 as 9 tap-GEMMs, t1(128) -> t2(128) =====
        {
            const int tr0 = (ncl12/7)*9 + (ncl12 - (ncl12/7)*7);
            f16v acc = {};
            #pragma unroll 1
            for (int ty = 0; ty < 3; ++ty) {
                #pragma unroll
                for (int tx = 0; tx < 3; ++tx) {
                    const int tap = ty*3 + tx;
                    bh8 aw[8];
                    #pragma unroll
                    for (int t = 0; t < 8; ++t) {
                        if (USE_WS) aw[t] = (ty == 0 && tx == 0 && t < 4) ? pf[t]
                                          : ld_bh8(ws + A2OFF + (((((ib*9+tap)*4 + mt12)*8 + t)*64 + lane) << 4));
                        else        aw[t] = gather8(w2 + ((size_t)(ib*BC + mt12*32 + ln)*BC + t*16 + 8*h)*9 + tap, 9);
                    }
                    const int row = tr0 + ty*9 + tx;
                    const unsigned char* bb = smem + T1_OFF + row*256;
                    const int rs = SWZ(row);
                    #pragma unroll
                    for (int t = 0; t < 8; ++t) {
                        bh8 b = ld_bh8(bb + ((t*32 + cb) ^ rs));
                        acc = __builtin_amdgcn_mfma_f32_32x32x16_bf16(aw[t], b, acc, 0, 0, 0);
                    }
                }
            }
            if (col12 < 49) {
                epi_store(acc, mt12*32, h, s2 + ib*BC, b2 + ib*BC,
                          smem + T2_OFF + col12*256, SWZ(col12));
            }
        }
        if (USE_WS) {   // prefetch conv3 a0 t=0..3
            #pragma unroll
            for (int t = 0; t < 4; ++t)
                pf[t] = ld_bh8(ws + A3OFF + ((((ib*8 + 2*mg+0)*8 + t)*64 + lane) << 4));
        }
        BAR();

        // ===== conv3: t2(128) -> xs(256) + residual + relu =====
        {
            const unsigned char* bb = smem + T2_OFF + ncl3 * 256;
            const int bswz = SWZ(ncl3);
            f16v acc0 = {}, acc1 = {};
            #pragma unroll
            for (int t = 0; t < 8; ++t) {
                bh8 a0, a1;
                if (USE_WS) {
                    a0 = (t < 4) ? pf[t]
                                 : ld_bh8(ws + A3OFF + ((((ib*8 + 2*mg+0)*8 + t)*64 + lane) << 4));
                    a1 = ld_bh8(ws + A3OFF + ((((ib*8 + 2*mg+1)*8 + t)*64 + lane) << 4));
                } else {
                    a0 = cvt8(w3 + (size_t)(ib*CH + (2*mg+0)*32 + ln)*BC + t*16 + 8*h);
                    a1 = cvt8(w3 + (size_t)(ib*CH + (2*mg+1)*32 + ln)*BC + t*16 + 8*h);
                }
                bh8 b = ld_bh8(bb + ((t*32 + cb) ^ bswz));
                acc0 = __builtin_amdgcn_mfma_f32_32x32x16_bf16(a0, b, acc0, 0, 0, 0);
                acc1 = __builtin_amdgcn_mfma_f32_32x32x16_bf16(a1, b, acc1, 0, 0, 0);
            }
            if (col3 < 49) {
                unsigned char* rowb = smem + XS_OFF + col3*512;
                const int rs = SWZ(col3);
                epi_res(acc0, (2*mg+0)*32, h, s3 + ib*CH, b3 + ib*CH, rowb, rs);
                epi_res(acc1, (2*mg+1)*32, h, s3 + ib*CH, b3 + ib*CH, rowb, rs);
            }
        }
        if (USE_WS) {   // prefetch next conv1 (ib+1) or deconv quad0
            #pragma unroll
            for (int t = 0; t < 4; ++t) {
                if (ib < NB - 1)
                    pf[t] = ld_bh8(ws + A1OFF + (((((ib+1)*4 + mt12)*16 + t)*64 + lane) << 4));
                else
                    pf[t] = ld_bh8(ws + ATOFF + ((((0*8 + 2*mg+0)*16 + t)*64 + lane) << 4));
            }
        }
        BAR();
    }

    // ---- Phase D: deconv 4 quads, B-panel hoisted to registers (read LDS once) ----
    {
        const unsigned char* bb = smem + XS_OFF + ncl3 * 512;
        const int bswz = SWZ(ncl3);
        bh8 bf[16];
        #pragma unroll
        for (int t = 0; t < 16; ++t)
            bf[t] = ld_bh8(bb + ((t*32 + cb) ^ bswz));
        #pragma unroll 1
        for (int quad = 0; quad < 4; ++quad) {
            f16v acc0 = {}, acc1 = {};
            #pragma unroll
            for (int t = 0; t < 16; ++t) {
                bh8 a0, a1;
                if (USE_WS) {
                    a0 = (quad == 0 && t < 4) ? pf[t]
                                 : ld_bh8(ws + ATOFF + ((((quad*8 + 2*mg+0)*16 + t)*64 + lane) << 4));
                    a1 = ld_bh8(ws + ATOFF + ((((quad*8 + 2*mg+1)*16 + t)*64 + lane) << 4));
                } else {
                    a0 = gather8(wt + (size_t)(t*16 + 8*h)*1024 + ((2*mg+0)*32 + ln)*4 + quad, 1024);
                    a1 = gather8(wt + (size_t)(t*16 + 8*h)*1024 + ((2*mg+1)*32 + ln)*4 + quad, 1024);
                }
                acc0 = __builtin_amdgcn_mfma_f32_32x32x16_bf16(a0, bf[t], acc0, 0, 0, 0);
                acc1 = __builtin_amdgcn_mfma_f32_32x32x16_bf16(a1, bf[t], acc1, 0, 0, 0);
            }
            float p0 = dq_part(acc0, (2*mg+0)*32, h, bt, wm)
                     + dq_part(acc1, (2*mg+1)*32, h, bt, wm);
            p0 += __shfl_down(p0, 32);
            if (h == 0 && col3 < 49) lgf[(quad*4 + mg)*64 + col3] = p0;
        }
    }
    BAR();

    // ---- final: sigmoid + scatter to 14x14 ----
    if (tid < 196) {
        const int quad = tid / 49, s = tid - quad*49;
        const float val = lgf[(quad*4+0)*64 + s] + lgf[(quad*4+1)*64 + s]
                        + lgf[(quad*4+2)*64 + s] + lgf[(quad*4+3)*64 + s] + bm[0];
        const int p = s / 7, q = s - p*7;
        const int dy = quad >> 1, dx = quad & 1;
        out[(size_t)r * 196 + (2*p + dy)*14 + (2*q + dx)] = 1.f / (1.f + expf(-val));
    }
}

extern "C" void kernel_launch(void* const* d_in, const int* in_sizes, int n_in,
                              void* d_out, int out_size, void* d_ws, size_t ws_size,
                              hipStream_t stream) {
    const float* feat = (const float*)d_in[0];
    const float* bbox = (const float*)d_in[1];
    const float* w1   = (const float*)d_in[2];
    const float* s1   = (const float*)d_in[3];
    const float* b1   = (const float*)d_in[4];
    const float* w2   = (const float*)d_in[5];
    const float* s2   = (const float*)d_in[6];
    const float* b2   = (const float*)d_in[7];
    const float* w3   = (const float*)d_in[8];
    const float* s3   = (const float*)d_in[9];
    const float* b3   = (const float*)d_in[10];
    const float* wt   = (const float*)d_in[11];
    const float* bt   = (const float*)d_in[12];
    const float* wm   = (const float*)d_in[13];
    const float* bm   = (const float*)d_in[14];
    float* out = (float*)d_out;

    if (ws_size >= (size_t)WS_FULL) {
        unsigned char* ws = (unsigned char*)d_ws;
        hipLaunchKernelGGL(prep_all, dim3(1024), dim3(256), 0, stream,
                           feat, w1, w2, w3, wt, ws, 1);
        hipLaunchKernelGGL((masknet_mfma<1,1>), dim3(NROI), dim3(NT), 0, stream,
                           feat, bbox, w1, s1, b1, w2, s2, b2, w3, s3, b3,
                           wt, bt, wm, bm, ws, out);
    } else if (ws_size >= (size_t)WS_BYTES) {
        unsigned char* ws = (unsigned char*)d_ws;
        hipLaunchKernelGGL(prep_all, dim3(448), dim3(256), 0, stream,
                           feat, w1, w2, w3, wt, ws, 0);
        hipLaunchKernelGGL((masknet_mfma<1,0>), dim3(NROI), dim3(NT), 0, stream,
                           feat, bbox, w1, s1, b1, w2, s2, b2, w3, s3, b3,
                           wt, bt, wm, bm, ws, out);
    } else {
        hipLaunchKernelGGL((masknet_mfma<0,0>), dim3(NROI), dim3(NT), 0, stream,
                           feat, bbox, w1, s1, b1, w2, s2, b2, w3, s3, b3,
                           wt, bt, wm, bm, (const unsigned char*)nullptr, out);
    }
}

// Round 15
// 115.071 us; speedup vs baseline: 1.1152x; 1.1152x over previous
//
#include <hip/hip_runtime.h>
#include <math.h>

#define RESQ 7
#define CH   256
#define NROI 512
#define BC   128
#define NB   3
#define NT   512

typedef __bf16 bh8  __attribute__((ext_vector_type(8)));
typedef float  f16v __attribute__((ext_vector_type(16)));

// LDS-only barrier: drain LDS counter, NOT vmcnt -> global prefetch stays in flight
#define BAR() do { \
    asm volatile("s_waitcnt lgkmcnt(0)" ::: "memory"); \
    __builtin_amdgcn_s_barrier(); \
    asm volatile("" ::: "memory"); \
} while (0)

// ---- d_ws layout (bytes): fragment-major A panels ----
#define A1OFF 0            // [3 ib][4 mt][16 t][64 lane][8] bf16 = 196608
#define A2OFF 196608       // [3][9 tap][4 mt][8 t][64][8]       = 884736
#define A3OFF 1081344      // [3][8 mt][8 t][64][8]              = 196608
#define ATOFF 1277952      // [4 quad][8 mt][16 t][64][8]        = 524288
#define WS_BYTES 1802240
#define FTOFF 1802240      // feat_t [16][36][36][256] bf16 -> 10616832 B
#define WS_FULL 12419072
#define PRE_ELEMS 901120

// ---- LDS (bytes), 2 ROIs per block ----
#define XS_OFF 0           // xs [2][49][256ch] bf16, row stride 512, rr stride 25088
#define XS_RR  25088
#define T1_OFF 50176       // t1 [2][81][128ch] bf16, row stride 256, rr stride 20736
#define T1_RR  20736
#define T2_OFF 91648       // t2 [2][49][128ch] bf16, row stride 256, rr stride 12544
#define T2_RR  12544
#define WY_OFF 116736      // 2 x 252 f32 (rr stride 1008)
#define WX_OFF 118752      // 2 x 252 f32
#define LG_OFF 120768      // 2 x [4 quad][4 mg][64] f32 (rr stride 4096)
#define LDS_BYTES 128960

#define SWZ(row) (((row) & 15) << 4)

__device__ __forceinline__ float Fk(float t) {
    t = fminf(1.f, fmaxf(-1.f, t));
    float a = t + 1.f, b = 1.f - t;
    return (t < 0.f) ? 0.5f * a * a : 1.f - 0.5f * b * b;
}
__device__ __forceinline__ unsigned short bf16bits(float a) {
    return __builtin_bit_cast(unsigned short, (__bf16)a);
}
__device__ __forceinline__ unsigned int pk2(float a, float b) {
    return (unsigned int)bf16bits(a) | ((unsigned int)bf16bits(b) << 16);
}
__device__ __forceinline__ float b2f(unsigned int s) {
    return __builtin_bit_cast(float, s << 16);
}
__device__ __forceinline__ bh8 ld_bh8(const unsigned char* p) { return *(const bh8*)p; }
__device__ __forceinline__ bh8 cvt8(const float* p) {
    float4 a = *(const float4*)p;
    float4 b = *(const float4*)(p + 4);
    bh8 r;
    r[0]=(__bf16)a.x; r[1]=(__bf16)a.y; r[2]=(__bf16)a.z; r[3]=(__bf16)a.w;
    r[4]=(__bf16)b.x; r[5]=(__bf16)b.y; r[6]=(__bf16)b.z; r[7]=(__bf16)b.w;
    return r;
}
__device__ __forceinline__ bh8 gather8(const float* p, int stride) {
    bh8 r;
    #pragma unroll
    for (int j = 0; j < 8; ++j) r[j] = (__bf16)p[j * stride];
    return r;
}

// epilogue helpers (compile-time reg indices only)
__device__ __forceinline__ void epi_store(const f16v acc, int chbase, int h,
        const float* sarr, const float* barr, unsigned char* rowbase, int rswz) {
    #pragma unroll
    for (int g = 0; g < 4; ++g) {
        const int ch = chbase + 8*g + 4*h;
        const float4 sv = *(const float4*)(sarr + ch);
        const float4 bv = *(const float4*)(barr + ch);
        float v0 = fmaxf(fmaf(acc[4*g+0], sv.x, bv.x), 0.f);
        float v1 = fmaxf(fmaf(acc[4*g+1], sv.y, bv.y), 0.f);
        float v2 = fmaxf(fmaf(acc[4*g+2], sv.z, bv.z), 0.f);
        float v3 = fmaxf(fmaf(acc[4*g+3], sv.w, bv.w), 0.f);
        *(uint2*)(rowbase + ((2*ch) ^ rswz)) = make_uint2(pk2(v0,v1), pk2(v2,v3));
    }
}
__device__ __forceinline__ void epi_res(const f16v acc, int chbase, int h,
        const float* sarr, const float* barr, unsigned char* rowbase, int rswz) {
    #pragma unroll
    for (int g = 0; g < 4; ++g) {
        const int ch = chbase + 8*g + 4*h;
        const float4 sv = *(const float4*)(sarr + ch);
        const float4 bv = *(const float4*)(barr + ch);
        unsigned char* p = rowbase + ((2*ch) ^ rswz);
        const uint2 old = *(const uint2*)p;
        float v0 = fmaxf(fmaf(acc[4*g+0], sv.x, bv.x) + b2f(old.x & 0xFFFFu), 0.f);
        float v1 = fmaxf(fmaf(acc[4*g+1], sv.y, bv.y) + b2f(old.x >> 16), 0.f);
        float v2 = fmaxf(fmaf(acc[4*g+2], sv.z, bv.z) + b2f(old.y & 0xFFFFu), 0.f);
        float v3 = fmaxf(fmaf(acc[4*g+3], sv.w, bv.w) + b2f(old.y >> 16), 0.f);
        *(uint2*)p = make_uint2(pk2(v0,v1), pk2(v2,v3));
    }
}
__device__ __forceinline__ float dq_part(const f16v acc, int chbase, int h,
        const float* bt, const float* wm) {
    float part = 0.f;
    #pragma unroll
    for (int g = 0; g < 4; ++g) {
        const int ch = chbase + 8*g + 4*h;
        const float4 btv = *(const float4*)(bt + ch);
        const float4 wmv = *(const float4*)(wm + ch);
        part = fmaf(wmv.x, fmaxf(acc[4*g+0] + btv.x, 0.f), part);
        part = fmaf(wmv.y, fmaxf(acc[4*g+1] + btv.y, 0.f), part);
        part = fmaf(wmv.z, fmaxf(acc[4*g+2] + btv.z, 0.f), part);
        part = fmaf(wmv.w, fmaxf(acc[4*g+3] + btv.w, 0.f), part);
    }
    return part;
}

// ---------------- prepass: fragment-major weights + feat transpose ----------------
extern "C" __global__ void prep_all(const float* __restrict__ feat,
                                    const float* __restrict__ w1,
                                    const float* __restrict__ w2,
                                    const float* __restrict__ w3,
                                    const float* __restrict__ wt,
                                    unsigned char* __restrict__ ws,
                                    int do_ft) {
    __shared__ unsigned short tile[36 * 256];
    if (do_ft && blockIdx.x < 576) {
        const int b = blockIdx.x / 36, y = blockIdx.x % 36;
        const int c = threadIdx.x;  // 256 threads
        const float* src = feat + (size_t)(b * 256 + c) * 1296 + y * 36;
        float4 fv[9];
        #pragma unroll
        for (int i = 0; i < 9; ++i) fv[i] = *(const float4*)(src + i * 4);
        #pragma unroll
        for (int i = 0; i < 9; ++i) {
            tile[(i*4+0)*256 + c] = bf16bits(fv[i].x);
            tile[(i*4+1)*256 + c] = bf16bits(fv[i].y);
            tile[(i*4+2)*256 + c] = bf16bits(fv[i].z);
            tile[(i*4+3)*256 + c] = bf16bits(fv[i].w);
        }
        __syncthreads();
        unsigned short* dst = (unsigned short*)(ws + FTOFF) + (size_t)(b*36 + y)*36*256;
        for (int x = 0; x < 36; ++x) dst[x*256 + c] = tile[x*256 + c];
        return;
    }
    const int base = do_ft ? 576 : 0;
    const int nb = gridDim.x - base;
    __bf16* wb = (__bf16*)ws;
    for (int i = (blockIdx.x - base) * blockDim.x + threadIdx.x; i < PRE_ELEMS;
         i += nb * blockDim.x) {
        float v; int dst;
        if (i < 98304) {                       // A1 frag
            int e = i;
            int j = e & 7, lane = (e>>3)&63, t = (e>>9)&15, mt = (e>>13)&3, ib = e>>15;
            int m = mt*32 + (lane&31), k = t*16 + 8*(lane>>5) + j;
            v = w1[(ib*BC + m)*CH + k];
            dst = (A1OFF>>1) + e;
        } else if (i < 98304 + 442368) {       // A2 frag (tap-major)
            int e = i - 98304;
            int j = e & 7, lane = (e>>3)&63, t = (e>>9)&7, mt = (e>>12)&3;
            int rem = e >> 14;                 // ib*9 + tap
            int ib = rem / 9, tap = rem - ib*9;
            int m = mt*32 + (lane&31), ci = t*16 + 8*(lane>>5) + j;
            v = w2[((ib*BC + m)*BC + ci)*9 + tap];
            dst = (A2OFF>>1) + e;
        } else if (i < 98304 + 442368 + 98304) { // A3 frag
            int e = i - (98304 + 442368);
            int j = e & 7, lane = (e>>3)&63, t = (e>>9)&7, mt = (e>>12)&7, ib = e>>15;
            int m = mt*32 + (lane&31), ci = t*16 + 8*(lane>>5) + j;
            v = w3[(ib*CH + m)*BC + ci];
            dst = (A3OFF>>1) + e;
        } else {                                // AT frag
            int e = i - (98304 + 442368 + 98304);
            int j = e & 7, lane = (e>>3)&63, t = (e>>9)&15, mt = (e>>13)&7, quad = e>>16;
            int co = mt*32 + (lane&31), ci = t*16 + 8*(lane>>5) + j;
            v = wt[ci*1024 + co*4 + quad];
            dst = (ATOFF>>1) + e;
        }
        wb[dst] = (__bf16)v;
    }
}

// ---------------- fused main kernel: 2 ROIs per block, A-frags shared ----------------
template<int USE_WS, int USE_FT>
__global__ __launch_bounds__(NT, 2)
void masknet_mfma(const float* __restrict__ feat,
                  const float* __restrict__ bbox,
                  const float* __restrict__ w1, const float* __restrict__ s1, const float* __restrict__ b1,
                  const float* __restrict__ w2, const float* __restrict__ s2, const float* __restrict__ b2,
                  const float* __restrict__ w3, const float* __restrict__ s3, const float* __restrict__ b3,
                  const float* __restrict__ wt, const float* __restrict__ bt,
                  const float* __restrict__ wm, const float* __restrict__ bm,
                  const unsigned char* __restrict__ ws,
                  float* __restrict__ out)
{
    __shared__ __align__(16) unsigned char smem[LDS_BYTES];

    const int tid  = threadIdx.x;
    const int r0   = blockIdx.x * 2;      // 2 ROIs per block (same frame)
    const int bfr  = r0 >> 5;
    const int lane = tid & 63;
    const int ln   = lane & 31;
    const int h    = lane >> 5;
    const int w_   = tid >> 6;
    const int cb   = 16 * h;
    const float S  = 1.f / 16.f;

    // ---- Phase A: tables (both ROIs) + zero t1 + zero logits ----
    #pragma unroll
    for (int rr = 0; rr < 2; ++rr) {
        const int r = r0 + rr;
        const float y1 = bbox[r*4+1] * S;
        const float x1 = bbox[r*4+0] * S;
        const float bwy = (bbox[r*4+3] * S) * (1.f / RESQ);
        const float bwx = (bbox[r*4+2] * S) * (1.f / RESQ);
        float* wyb = (float*)(smem + WY_OFF + rr*1008);
        float* wxb = (float*)(smem + WX_OFF + rr*1008);
        if (tid < 252) {
            int p = tid / 36, i = tid - p * 36;
            float st = y1 + bwy * p, en = st + bwy;
            wyb[tid] = Fk(en - (float)i) - Fk(st - (float)i);
        } else if (tid >= 256 && tid < 508) {
            int t = tid - 256;
            int q = t / 36, i = t - q * 36;
            float st = x1 + bwx * q, en = st + bwx;
            wxb[t] = Fk(en - (float)i) - Fk(st - (float)i);
        }
    }
    {
        uint4* z = (uint4*)(smem + T1_OFF);
        for (int o = tid; o < 2592; o += NT) z[o] = make_uint4(0,0,0,0);
        float* lg = (float*)(smem + LG_OFF);
        for (int o = tid; o < 2048; o += NT) lg[o] = 0.f;
    }
    BAR();

    // ---- Phase B: PrRoI pool for both ROIs -> xs[rr][s][c] bf16 (swizzled) ----
    #pragma unroll
    for (int rr = 0; rr < 2; ++rr) {
        const int r = r0 + rr;
        const float y1 = bbox[r*4+1] * S;
        const float x1 = bbox[r*4+0] * S;
        const float bwy = (bbox[r*4+3] * S) * (1.f / RESQ);
        const float bwx = (bbox[r*4+2] * S) * (1.f / RESQ);
        const float area = bwx * bwy;
        const float inv_area = (area > 0.f) ? 1.f / fmaxf(area, 1e-12f) : 0.f;
        float* wyb = (float*)(smem + WY_OFF + rr*1008);
        float* wxb = (float*)(smem + WX_OFF + rr*1008);
        if (USE_FT) {
            const unsigned short* ft = (const unsigned short*)(ws + FTOFF) + (size_t)bfr * (1296 * 256);
            const int g = w_ * 2 + h;   // 0..15
            #pragma unroll 1
            for (int k = 0; k < 4; ++k) {
                const int s = g + 16 * k;
                if (s >= 49) break;
                const int p = s / 7, q = s - p * 7;
                const float sy = y1 + bwy * p, sx = x1 + bwx * q;
                const int ylo = max(0, (int)floorf(sy)), yhi = min(35, (int)ceilf(sy + bwy));
                const int xlo = max(0, (int)floorf(sx)), xhi = min(35, (int)ceilf(sx + bwx));
                float wyv[4], wxv[4];
                #pragma unroll
                for (int j = 0; j < 4; ++j) {
                    const int y = ylo + j, x = xlo + j;
                    wyv[j] = (y <= yhi) ? wyb[p*36 + y] * inv_area : 0.f;
                    wxv[j] = (x <= xhi) ? wxb[q*36 + x] : 0.f;
                }
                float ac0=0.f,ac1=0.f,ac2=0.f,ac3=0.f,ac4=0.f,ac5=0.f,ac6=0.f,ac7=0.f;
                #pragma unroll
                for (int yy = 0; yy < 4; ++yy) {
                    const int y = min(ylo + yy, 35);
                    const unsigned short* rowp = ft + (size_t)(y * 36) * 256 + ln * 8;
                    #pragma unroll
                    for (int xx = 0; xx < 4; ++xx) {
                        const int x = min(xlo + xx, 35);
                        const float wgt = wyv[yy] * wxv[xx];
                        const uint4 v = *(const uint4*)(rowp + x * 256);
                        ac0 = fmaf(wgt, b2f(v.x & 0xFFFFu), ac0);
                        ac1 = fmaf(wgt, b2f(v.x >> 16),     ac1);
                        ac2 = fmaf(wgt, b2f(v.y & 0xFFFFu), ac2);
                        ac3 = fmaf(wgt, b2f(v.y >> 16),     ac3);
                        ac4 = fmaf(wgt, b2f(v.z & 0xFFFFu), ac4);
                        ac5 = fmaf(wgt, b2f(v.z >> 16),     ac5);
                        ac6 = fmaf(wgt, b2f(v.w & 0xFFFFu), ac6);
                        ac7 = fmaf(wgt, b2f(v.w >> 16),     ac7);
                    }
                }
                *(uint4*)(smem + XS_OFF + rr*XS_RR + s * 512 + ((16 * ln) ^ SWZ(s))) =
                    make_uint4(pk2(ac0,ac1), pk2(ac2,ac3), pk2(ac4,ac5), pk2(ac6,ac7));
            }
        } else {
            const float* fb = feat + (size_t)bfr * CH * 36 * 36;
            for (int o = tid; o < CH * 49; o += NT) {
                int c = o / 49, s = o - c * 49;
                int p = s / 7, q = s - p * 7;
                float sy = y1 + bwy * p, sx = x1 + bwx * q;
                int ylo = max(0, (int)floorf(sy)), yhi = min(35, (int)ceilf(sy + bwy));
                int xlo = max(0, (int)floorf(sx)), xhi = min(35, (int)ceilf(sx + bwx));
                const float* fc = fb + c * 1296;
                float acc = 0.f;
                for (int y = ylo; y <= yhi; ++y) {
                    float wyv = wyb[p * 36 + y];
                    for (int x = xlo; x <= xhi; ++x)
                        acc = fmaf(wyv * wxb[q * 36 + x], fc[y * 36 + x], acc);
                }
                *(unsigned short*)(smem + XS_OFF + rr*XS_RR + s * 512 + ((2 * c) ^ SWZ(s))) =
                    bf16bits(acc * inv_area);
            }
        }
    }

    // wave geometry
    const int mt12 = w_ & 3, nt12 = w_ >> 2;           // conv1/2: 4m x 2n
    const int col12 = nt12 * 32 + ln;
    const int ncl12 = min(col12, 48);
    const int mg = w_ >> 1, ng = w_ & 1;               // conv3/deconv: (2 mt) x 2n
    const int col3 = ng * 32 + ln;
    const int ncl3 = min(col3, 48);

    // prefetch: first 4 A-frags of the upcoming phase, issued pre-barrier
    bh8 pf[4] = {};
    if (USE_WS) {
        #pragma unroll
        for (int t = 0; t < 4; ++t)
            pf[t] = ld_bh8(ws + A1OFF + ((((0*4 + mt12)*16 + t)*64 + lane) << 4));
    }
    BAR();

    // ---- Phase C: bottleneck blocks (A shared across both ROIs) ----
    #pragma unroll 1
    for (int ib = 0; ib < NB; ++ib) {
        // ===== conv1: xs(256) -> t1(128 interior), A loaded once, 2 acc =====
        {
            const unsigned char* bb0 = smem + XS_OFF + 0*XS_RR + ncl12 * 512;
            const unsigned char* bb1 = smem + XS_OFF + 1*XS_RR + ncl12 * 512;
            const int bswz = SWZ(ncl12);
            f16v acc0 = {}, acc1 = {};
            #pragma unroll
            for (int t = 0; t < 16; ++t) {
                bh8 a;
                if (USE_WS) a = (t < 4) ? pf[t]
                                        : ld_bh8(ws + A1OFF + ((((ib*4 + mt12)*16 + t)*64 + lane) << 4));
                else        a = cvt8(w1 + (size_t)(ib*BC + mt12*32 + ln)*CH + t*16 + 8*h);
                bh8 b0 = ld_bh8(bb0 + ((t*32 + cb) ^ bswz));
                bh8 b1 = ld_bh8(bb1 + ((t*32 + cb) ^ bswz));
                acc0 = __builtin_amdgcn_mfma_f32_32x32x16_bf16(a, b0, acc0, 0, 0, 0);
                acc1 = __builtin_amdgcn_mfma_f32_32x32x16_bf16(a, b1, acc1, 0, 0, 0);
            }
            if (col12 < 49) {
                const int row = (col12/7 + 1)*9 + (col12 - (col12/7)*7) + 1;
                epi_store(acc0, mt12*32, h, s1 + ib*BC, b1 + ib*BC,
                          smem + T1_OFF + 0*T1_RR + row*256, SWZ(row));
                epi_store(acc1, mt12*32, h, s1 + ib*BC, b1 + ib*BC,
                          smem + T1_OFF + 1*T1_RR + row*256, SWZ(row));
            }
        }
        if (USE_WS) {   // prefetch conv2 tap0 t=0..3
            #pragma unroll
            for (int t = 0; t < 4; ++t)
                pf[t] = ld_bh8(ws + A2OFF + (((((ib*9+0)*4 + mt12)*8 + t)*64 + lane) << 4));
        }
        BAR();

        // ===== conv2: 3x3 as 9 tap-GEMMs, A per tap loaded once, 2 acc =====
        {
            const int tr0 = (ncl12/7)*9 + (ncl12 - (ncl12/7)*7);
            f16v acc0 = {}, acc1 = {};
            #pragma unroll 1
            for (int ty = 0; ty < 3; ++ty) {
                #pragma unroll
                for (int tx = 0; tx < 3; ++tx) {
                    const int tap = ty*3 + tx;
                    bh8 aw[8];
                    #pragma unroll
                    for (int t = 0; t < 8; ++t) {
                        if (USE_WS) aw[t] = (ty == 0 && tx == 0 && t < 4) ? pf[t]
                                          : ld_bh8(ws + A2OFF + (((((ib*9+tap)*4 + mt12)*8 + t)*64 + lane) << 4));
                        else        aw[t] = gather8(w2 + ((size_t)(ib*BC + mt12*32 + ln)*BC + t*16 + 8*h)*9 + tap, 9);
                    }
                    const int row = tr0 + ty*9 + tx;
                    const unsigned char* bb0 = smem + T1_OFF + 0*T1_RR + row*256;
                    const unsigned char* bb1 = smem + T1_OFF + 1*T1_RR + row*256;
                    const int rs = SWZ(row);
                    #pragma unroll
                    for (int t = 0; t < 8; ++t) {
                        bh8 b0 = ld_bh8(bb0 + ((t*32 + cb) ^ rs));
                        bh8 b1 = ld_bh8(bb1 + ((t*32 + cb) ^ rs));
                        acc0 = __builtin_amdgcn_mfma_f32_32x32x16_bf16(aw[t], b0, acc0, 0, 0, 0);
                        acc1 = __builtin_amdgcn_mfma_f32_32x32x16_bf16(aw[t], b1, acc1, 0, 0, 0);
                    }
                }
            }
            if (col12 < 49) {
                epi_store(acc0, mt12*32, h, s2 + ib*BC, b2 + ib*BC,
                          smem + T2_OFF + 0*T2_RR + col12*256, SWZ(col12));
                epi_store(acc1, mt12*32, h, s2 + ib*BC, b2 + ib*BC,
                          smem + T2_OFF + 1*T2_RR + col12*256, SWZ(col12));
            }
        }
        if (USE_WS) {   // prefetch conv3 a0 t=0..3
            #pragma unroll
            for (int t = 0; t < 4; ++t)
                pf[t] = ld_bh8(ws + A3OFF + ((((ib*8 + 2*mg+0)*8 + t)*64 + lane) << 4));
        }
        BAR();

        // ===== conv3: t2(128) -> xs(256) + residual, A shared, 4 acc =====
        {
            const unsigned char* bb0 = smem + T2_OFF + 0*T2_RR + ncl3 * 256;
            const unsigned char* bb1 = smem + T2_OFF + 1*T2_RR + ncl3 * 256;
            const int bswz = SWZ(ncl3);
            f16v acc00 = {}, acc01 = {}, acc10 = {}, acc11 = {};   // [mtile][rr]
            #pragma unroll
            for (int t = 0; t < 8; ++t) {
                bh8 a0, a1;
                if (USE_WS) {
                    a0 = (t < 4) ? pf[t]
                                 : ld_bh8(ws + A3OFF + ((((ib*8 + 2*mg+0)*8 + t)*64 + lane) << 4));
                    a1 = ld_bh8(ws + A3OFF + ((((ib*8 + 2*mg+1)*8 + t)*64 + lane) << 4));
                } else {
                    a0 = cvt8(w3 + (size_t)(ib*CH + (2*mg+0)*32 + ln)*BC + t*16 + 8*h);
                    a1 = cvt8(w3 + (size_t)(ib*CH + (2*mg+1)*32 + ln)*BC + t*16 + 8*h);
                }
                bh8 b0 = ld_bh8(bb0 + ((t*32 + cb) ^ bswz));
                bh8 b1 = ld_bh8(bb1 + ((t*32 + cb) ^ bswz));
                acc00 = __builtin_amdgcn_mfma_f32_32x32x16_bf16(a0, b0, acc00, 0, 0, 0);
                acc01 = __builtin_amdgcn_mfma_f32_32x32x16_bf16(a0, b1, acc01, 0, 0, 0);
                acc10 = __builtin_amdgcn_mfma_f32_32x32x16_bf16(a1, b0, acc10, 0, 0, 0);
                acc11 = __builtin_amdgcn_mfma_f32_32x32x16_bf16(a1, b1, acc11, 0, 0, 0);
            }
            if (col3 < 49) {
                const int rs = SWZ(col3);
                unsigned char* rb0 = smem + XS_OFF + 0*XS_RR + col3*512;
                unsigned char* rb1 = smem + XS_OFF + 1*XS_RR + col3*512;
                epi_res(acc00, (2*mg+0)*32, h, s3 + ib*CH, b3 + ib*CH, rb0, rs);
                epi_res(acc10, (2*mg+1)*32, h, s3 + ib*CH, b3 + ib*CH, rb0, rs);
                epi_res(acc01, (2*mg+0)*32, h, s3 + ib*CH, b3 + ib*CH, rb1, rs);
                epi_res(acc11, (2*mg+1)*32, h, s3 + ib*CH, b3 + ib*CH, rb1, rs);
            }
        }
        if (USE_WS) {   // prefetch next conv1 (ib+1) or deconv quad0
            #pragma unroll
            for (int t = 0; t < 4; ++t) {
                if (ib < NB - 1)
                    pf[t] = ld_bh8(ws + A1OFF + (((((ib+1)*4 + mt12)*16 + t)*64 + lane) << 4));
                else
                    pf[t] = ld_bh8(ws + ATOFF + ((((0*8 + 2*mg+0)*16 + t)*64 + lane) << 4));
            }
        }
        BAR();
    }

    // ---- Phase D: deconv 4 quads, A shared across both ROIs, fused mask head ----
    {
        const unsigned char* bb0 = smem + XS_OFF + 0*XS_RR + ncl3 * 512;
        const unsigned char* bb1 = smem + XS_OFF + 1*XS_RR + ncl3 * 512;
        const int bswz = SWZ(ncl3);
        #pragma unroll 1
        for (int quad = 0; quad < 4; ++quad) {
            f16v acc00 = {}, acc01 = {}, acc10 = {}, acc11 = {};   // [mtile][rr]
            #pragma unroll
            for (int t = 0; t < 16; ++t) {
                bh8 a0, a1;
                if (USE_WS) {
                    a0 = (quad == 0 && t < 4) ? pf[t]
                                 : ld_bh8(ws + ATOFF + ((((quad*8 + 2*mg+0)*16 + t)*64 + lane) << 4));
                    a1 = ld_bh8(ws + ATOFF + ((((quad*8 + 2*mg+1)*16 + t)*64 + lane) << 4));
                } else {
                    a0 = gather8(wt + (size_t)(t*16 + 8*h)*1024 + ((2*mg+0)*32 + ln)*4 + quad, 1024);
                    a1 = gather8(wt + (size_t)(t*16 + 8*h)*1024 + ((2*mg+1)*32 + ln)*4 + quad, 1024);
                }
                bh8 b0 = ld_bh8(bb0 + ((t*32 + cb) ^ bswz));
                bh8 b1 = ld_bh8(bb1 + ((t*32 + cb) ^ bswz));
                acc00 = __builtin_amdgcn_mfma_f32_32x32x16_bf16(a0, b0, acc00, 0, 0, 0);
                acc01 = __builtin_amdgcn_mfma_f32_32x32x16_bf16(a0, b1, acc01, 0, 0, 0);
                acc10 = __builtin_amdgcn_mfma_f32_32x32x16_bf16(a1, b0, acc10, 0, 0, 0);
                acc11 = __builtin_amdgcn_mfma_f32_32x32x16_bf16(a1, b1, acc11, 0, 0, 0);
            }
            float p0 = dq_part(acc00, (2*mg+0)*32, h, bt, wm)
                     + dq_part(acc10, (2*mg+1)*32, h, bt, wm);
            float p1 = dq_part(acc01, (2*mg+0)*32, h, bt, wm)
                     + dq_part(acc11, (2*mg+1)*32, h, bt, wm);
            p0 += __shfl_down(p0, 32);
            p1 += __shfl_down(p1, 32);
            if (h == 0 && col3 < 49) {
                ((float*)(smem + LG_OFF + 0*4096))[(quad*4 + mg)*64 + col3] = p0;
                ((float*)(smem + LG_OFF + 1*4096))[(quad*4 + mg)*64 + col3] = p1;
            }
        }
    }
    BAR();

    // ---- final: sigmoid + scatter to 14x14 for both ROIs ----
    #pragma unroll
    for (int rr = 0; rr < 2; ++rr) {
        if (tid < 196) {
            const float* lg = (const float*)(smem + LG_OFF + rr*4096);
            const int quad = tid / 49, s = tid - quad*49;
            const float val = lg[(quad*4+0)*64 + s] + lg[(quad*4+1)*64 + s]
                            + lg[(quad*4+2)*64 + s] + lg[(quad*4+3)*64 + s] + bm[0];
            const int p = s / 7, q = s - p*7;
            const int dy = quad >> 1, dx = quad & 1;
            out[(size_t)(r0 + rr) * 196 + (2*p + dy)*14 + (2*q + dx)] =
                1.f / (1.f + expf(-val));
        }
    }
}

extern "C" void kernel_launch(void* const* d_in, const int* in_sizes, int n_in,
                              void* d_out, int out_size, void* d_ws, size_t ws_size,
                              hipStream_t stream) {
    const float* feat = (const float*)d_in[0];
    const float* bbox = (const float*)d_in[1];
    const float* w1   = (const float*)d_in[2];
    const float* s1   = (const float*)d_in[3];
    const float* b1   = (const float*)d_in[4];
    const float* w2   = (const float*)d_in[5];
    const float* s2   = (const float*)d_in[6];
    const float* b2   = (const float*)d_in[7];
    const float* w3   = (const float*)d_in[8];
    const float* s3   = (const float*)d_in[9];
    const float* b3   = (const float*)d_in[10];
    const float* wt   = (const float*)d_in[11];
    const float* bt   = (const float*)d_in[12];
    const float* wm   = (const float*)d_in[13];
    const float* bm   = (const float*)d_in[14];
    float* out = (float*)d_out;

    if (ws_size >= (size_t)WS_FULL) {
        unsigned char* ws = (unsigned char*)d_ws;
        hipLaunchKernelGGL(prep_all, dim3(1024), dim3(256), 0, stream,
                           feat, w1, w2, w3, wt, ws, 1);
        hipLaunchKernelGGL((masknet_mfma<1,1>), dim3(NROI/2), dim3(NT), 0, stream,
                           feat, bbox, w1, s1, b1, w2, s2, b2, w3, s3, b3,
                           wt, bt, wm, bm, ws, out);
    } else if (ws_size >= (size_t)WS_BYTES) {
        unsigned char* ws = (unsigned char*)d_ws;
        hipLaunchKernelGGL(prep_all, dim3(448), dim3(256), 0, stream,
                           feat, w1, w2, w3, wt, ws, 0);
        hipLaunchKernelGGL((masknet_mfma<1,0>), dim3(NROI/2), dim3(NT), 0, stream,
                           feat, bbox, w1, s1, b1, w2, s2, b2, w3, s3, b3,
                           wt, bt, wm, bm, ws, out);
    } else {
        hipLaunchKernelGGL((masknet_mfma<0,0>), dim3(NROI/2), dim3(NT), 0, stream,
                           feat, bbox, w1, s1, b1, w2, s2, b2, w3, s3, b3,
                           wt, bt, wm, bm, (const unsigned char*)nullptr, out);
    }
}

// Round 16
// 112.686 us; speedup vs baseline: 1.1388x; 1.0212x over previous
//
#include <hip/hip_runtime.h>
#include <math.h>

#define RESQ 7
#define CH   256
#define NROI 512
#define BC   128
#define NB   3
#define NT   512

typedef __bf16 bh8  __attribute__((ext_vector_type(8)));
typedef float  f16v __attribute__((ext_vector_type(16)));

// LDS-only barrier: drain LDS counter, NOT vmcnt -> global prefetch stays in flight
#define BAR() do { \
    asm volatile("s_waitcnt lgkmcnt(0)" ::: "memory"); \
    __builtin_amdgcn_s_barrier(); \
    asm volatile("" ::: "memory"); \
} while (0)

// ---- d_ws layout (bytes): fragment-major A panels ----
#define A1OFF 0            // [3 ib][4 mt][16 t][64 lane][8] bf16 = 196608
#define A2OFF 196608       // [3][9 tap][4 mt][8 t][64][8]       = 884736
#define A3OFF 1081344      // [3][8 mt][8 t][64][8]              = 196608
#define ATOFF 1277952      // [4 quad][8 mt][16 t][64][8]        = 524288
#define WS_BYTES 1802240
#define FTOFF 1802240      // feat_t [16][36][36][256] bf16 -> 10616832 B
#define WS_FULL 12419072
#define PRE_ELEMS 901120

// ---- LDS (bytes), 2 ROIs per block ----
#define XS_OFF 0           // xs [2][49][256ch] bf16, row stride 512, rr stride 25088
#define XS_RR  25088
#define T1_OFF 50176       // t1 [2][81][128ch] bf16, row stride 256, rr stride 20736
#define T1_RR  20736
#define T2_OFF 91648       // t2 [2][49][128ch] bf16, row stride 256, rr stride 12544
#define T2_RR  12544
#define WY_OFF 116736      // 2 x 252 f32 (rr stride 1008)
#define WX_OFF 118752      // 2 x 252 f32
#define LG_OFF 120768      // 2 x [4 quad][4 mg][64] f32 (rr stride 4096)
#define LDS_BYTES 128960

#define SWZ(row) (((row) & 15) << 4)

__device__ __forceinline__ float Fk(float t) {
    t = fminf(1.f, fmaxf(-1.f, t));
    float a = t + 1.f, b = 1.f - t;
    return (t < 0.f) ? 0.5f * a * a : 1.f - 0.5f * b * b;
}
__device__ __forceinline__ unsigned short bf16bits(float a) {
    return __builtin_bit_cast(unsigned short, (__bf16)a);
}
__device__ __forceinline__ unsigned int pk2(float a, float b) {
    return (unsigned int)bf16bits(a) | ((unsigned int)bf16bits(b) << 16);
}
__device__ __forceinline__ float b2f(unsigned int s) {
    return __builtin_bit_cast(float, s << 16);
}
__device__ __forceinline__ bh8 ld_bh8(const unsigned char* p) { return *(const bh8*)p; }
__device__ __forceinline__ bh8 cvt8(const float* p) {
    float4 a = *(const float4*)p;
    float4 b = *(const float4*)(p + 4);
    bh8 r;
    r[0]=(__bf16)a.x; r[1]=(__bf16)a.y; r[2]=(__bf16)a.z; r[3]=(__bf16)a.w;
    r[4]=(__bf16)b.x; r[5]=(__bf16)b.y; r[6]=(__bf16)b.z; r[7]=(__bf16)b.w;
    return r;
}
__device__ __forceinline__ bh8 gather8(const float* p, int stride) {
    bh8 r;
    #pragma unroll
    for (int j = 0; j < 8; ++j) r[j] = (__bf16)p[j * stride];
    return r;
}

// epilogue helpers (compile-time reg indices only)
__device__ __forceinline__ void epi_store(const f16v acc, int chbase, int h,
        const float* sarr, const float* barr, unsigned char* rowbase, int rswz) {
    #pragma unroll
    for (int g = 0; g < 4; ++g) {
        const int ch = chbase + 8*g + 4*h;
        const float4 sv = *(const float4*)(sarr + ch);
        const float4 bv = *(const float4*)(barr + ch);
        float v0 = fmaxf(fmaf(acc[4*g+0], sv.x, bv.x), 0.f);
        float v1 = fmaxf(fmaf(acc[4*g+1], sv.y, bv.y), 0.f);
        float v2 = fmaxf(fmaf(acc[4*g+2], sv.z, bv.z), 0.f);
        float v3 = fmaxf(fmaf(acc[4*g+3], sv.w, bv.w), 0.f);
        *(uint2*)(rowbase + ((2*ch) ^ rswz)) = make_uint2(pk2(v0,v1), pk2(v2,v3));
    }
}
__device__ __forceinline__ void epi_res(const f16v acc, int chbase, int h,
        const float* sarr, const float* barr, unsigned char* rowbase, int rswz) {
    #pragma unroll
    for (int g = 0; g < 4; ++g) {
        const int ch = chbase + 8*g + 4*h;
        const float4 sv = *(const float4*)(sarr + ch);
        const float4 bv = *(const float4*)(barr + ch);
        unsigned char* p = rowbase + ((2*ch) ^ rswz);
        const uint2 old = *(const uint2*)p;
        float v0 = fmaxf(fmaf(acc[4*g+0], sv.x, bv.x) + b2f(old.x & 0xFFFFu), 0.f);
        float v1 = fmaxf(fmaf(acc[4*g+1], sv.y, bv.y) + b2f(old.x >> 16), 0.f);
        float v2 = fmaxf(fmaf(acc[4*g+2], sv.z, bv.z) + b2f(old.y & 0xFFFFu), 0.f);
        float v3 = fmaxf(fmaf(acc[4*g+3], sv.w, bv.w) + b2f(old.y >> 16), 0.f);
        *(uint2*)p = make_uint2(pk2(v0,v1), pk2(v2,v3));
    }
}
__device__ __forceinline__ float dq_part(const f16v acc, int chbase, int h,
        const float* bt, const float* wm) {
    float part = 0.f;
    #pragma unroll
    for (int g = 0; g < 4; ++g) {
        const int ch = chbase + 8*g + 4*h;
        const float4 btv = *(const float4*)(bt + ch);
        const float4 wmv = *(const float4*)(wm + ch);
        part = fmaf(wmv.x, fmaxf(acc[4*g+0] + btv.x, 0.f), part);
        part = fmaf(wmv.y, fmaxf(acc[4*g+1] + btv.y, 0.f), part);
        part = fmaf(wmv.z, fmaxf(acc[4*g+2] + btv.z, 0.f), part);
        part = fmaf(wmv.w, fmaxf(acc[4*g+3] + btv.w, 0.f), part);
    }
    return part;
}

// ---------------- prepass: fragment-major weights + feat transpose ----------------
extern "C" __global__ void prep_all(const float* __restrict__ feat,
                                    const float* __restrict__ w1,
                                    const float* __restrict__ w2,
                                    const float* __restrict__ w3,
                                    const float* __restrict__ wt,
                                    unsigned char* __restrict__ ws,
                                    int do_ft) {
    __shared__ unsigned short tile[36 * 257];   // +1 pad: conflict-free both ways
    if (do_ft && blockIdx.x < 576) {
        // transpose one (frame, y) row-plane: feat[b][c][y][x] -> feat_t[b][y][x][c]
        // coalesced-ish reads: consecutive lanes cover consecutive float4s per row
        const int b = blockIdx.x / 36, y = blockIdx.x % 36;
        const int t = threadIdx.x;  // 256 threads
        const float* fb = feat + (size_t)b * 256 * 1296 + y * 36;
        #pragma unroll
        for (int k = 0; k < 9; ++k) {
            const int idx = k * 256 + t;         // 0..2303 = c*9 + xq
            const int c = idx / 9, xq = idx - 9 * c;
            const float4 v = *(const float4*)(fb + (size_t)c * 1296 + xq * 4);
            tile[(xq*4+0)*257 + c] = bf16bits(v.x);
            tile[(xq*4+1)*257 + c] = bf16bits(v.y);
            tile[(xq*4+2)*257 + c] = bf16bits(v.z);
            tile[(xq*4+3)*257 + c] = bf16bits(v.w);
        }
        __syncthreads();
        unsigned short* dst = (unsigned short*)(ws + FTOFF) + (size_t)(b*36 + y)*36*256;
        for (int x = 0; x < 36; ++x) dst[x*256 + t] = tile[x*257 + t];
        return;
    }
    const int base = do_ft ? 576 : 0;
    const int nb = gridDim.x - base;
    __bf16* wb = (__bf16*)ws;
    for (int i = (blockIdx.x - base) * blockDim.x + threadIdx.x; i < PRE_ELEMS;
         i += nb * blockDim.x) {
        float v; int dst;
        if (i < 98304) {                       // A1 frag
            int e = i;
            int j = e & 7, lane = (e>>3)&63, t = (e>>9)&15, mt = (e>>13)&3, ib = e>>15;
            int m = mt*32 + (lane&31), k = t*16 + 8*(lane>>5) + j;
            v = w1[(ib*BC + m)*CH + k];
            dst = (A1OFF>>1) + e;
        } else if (i < 98304 + 442368) {       // A2 frag (tap-major)
            int e = i - 98304;
            int j = e & 7, lane = (e>>3)&63, t = (e>>9)&7, mt = (e>>12)&3;
            int rem = e >> 14;                 // ib*9 + tap
            int ib = rem / 9, tap = rem - ib*9;
            int m = mt*32 + (lane&31), ci = t*16 + 8*(lane>>5) + j;
            v = w2[((ib*BC + m)*BC + ci)*9 + tap];
            dst = (A2OFF>>1) + e;
        } else if (i < 98304 + 442368 + 98304) { // A3 frag
            int e = i - (98304 + 442368);
            int j = e & 7, lane = (e>>3)&63, t = (e>>9)&7, mt = (e>>12)&7, ib = e>>15;
            int m = mt*32 + (lane&31), ci = t*16 + 8*(lane>>5) + j;
            v = w3[(ib*CH + m)*BC + ci];
            dst = (A3OFF>>1) + e;
        } else {                                // AT frag
            int e = i - (98304 + 442368 + 98304);
            int j = e & 7, lane = (e>>3)&63, t = (e>>9)&15, mt = (e>>13)&7, quad = e>>16;
            int co = mt*32 + (lane&31), ci = t*16 + 8*(lane>>5) + j;
            v = wt[ci*1024 + co*4 + quad];
            dst = (ATOFF>>1) + e;
        }
        wb[dst] = (__bf16)v;
    }
}

// ---------------- fused main kernel: 2 ROIs per block, A-frags shared ----------------
template<int USE_WS, int USE_FT>
__global__ __launch_bounds__(NT, 2)
void masknet_mfma(const float* __restrict__ feat,
                  const float* __restrict__ bbox,
                  const float* __restrict__ w1, const float* __restrict__ s1, const float* __restrict__ b1,
                  const float* __restrict__ w2, const float* __restrict__ s2, const float* __restrict__ b2,
                  const float* __restrict__ w3, const float* __restrict__ s3, const float* __restrict__ b3,
                  const float* __restrict__ wt, const float* __restrict__ bt,
                  const float* __restrict__ wm, const float* __restrict__ bm,
                  const unsigned char* __restrict__ ws,
                  float* __restrict__ out)
{
    __shared__ __align__(16) unsigned char smem[LDS_BYTES];

    const int tid  = threadIdx.x;
    const int r0   = blockIdx.x * 2;      // 2 ROIs per block (same frame)
    const int bfr  = r0 >> 5;
    const int lane = tid & 63;
    const int ln   = lane & 31;
    const int h    = lane >> 5;
    const int w_   = tid >> 6;
    const int cb   = 16 * h;
    const float S  = 1.f / 16.f;

    // ---- Phase A: tables (both ROIs) + zero t1 + zero logits ----
    #pragma unroll
    for (int rr = 0; rr < 2; ++rr) {
        const int r = r0 + rr;
        const float y1 = bbox[r*4+1] * S;
        const float x1 = bbox[r*4+0] * S;
        const float bwy = (bbox[r*4+3] * S) * (1.f / RESQ);
        const float bwx = (bbox[r*4+2] * S) * (1.f / RESQ);
        float* wyb = (float*)(smem + WY_OFF + rr*1008);
        float* wxb = (float*)(smem + WX_OFF + rr*1008);
        if (tid < 252) {
            int p = tid / 36, i = tid - p * 36;
            float st = y1 + bwy * p, en = st + bwy;
            wyb[tid] = Fk(en - (float)i) - Fk(st - (float)i);
        } else if (tid >= 256 && tid < 508) {
            int t = tid - 256;
            int q = t / 36, i = t - q * 36;
            float st = x1 + bwx * q, en = st + bwx;
            wxb[t] = Fk(en - (float)i) - Fk(st - (float)i);
        }
    }
    {
        uint4* z = (uint4*)(smem + T1_OFF);
        for (int o = tid; o < 2592; o += NT) z[o] = make_uint4(0,0,0,0);
        float* lg = (float*)(smem + LG_OFF);
        for (int o = tid; o < 2048; o += NT) lg[o] = 0.f;
    }
    BAR();

    // ---- Phase B: PrRoI pool for both ROIs -> xs[rr][s][c] bf16 (swizzled) ----
    #pragma unroll
    for (int rr = 0; rr < 2; ++rr) {
        const int r = r0 + rr;
        const float y1 = bbox[r*4+1] * S;
        const float x1 = bbox[r*4+0] * S;
        const float bwy = (bbox[r*4+3] * S) * (1.f / RESQ);
        const float bwx = (bbox[r*4+2] * S) * (1.f / RESQ);
        const float area = bwx * bwy;
        const float inv_area = (area > 0.f) ? 1.f / fmaxf(area, 1e-12f) : 0.f;
        float* wyb = (float*)(smem + WY_OFF + rr*1008);
        float* wxb = (float*)(smem + WX_OFF + rr*1008);
        if (USE_FT) {
            const unsigned short* ft = (const unsigned short*)(ws + FTOFF) + (size_t)bfr * (1296 * 256);
            const int g = w_ * 2 + h;   // 0..15
            #pragma unroll 1
            for (int k = 0; k < 4; ++k) {
                const int s = g + 16 * k;
                if (s >= 49) break;
                const int p = s / 7, q = s - p * 7;
                const float sy = y1 + bwy * p, sx = x1 + bwx * q;
                const int ylo = max(0, (int)floorf(sy)), yhi = min(35, (int)ceilf(sy + bwy));
                const int xlo = max(0, (int)floorf(sx)), xhi = min(35, (int)ceilf(sx + bwx));
                float wyv[4], wxv[4];
                #pragma unroll
                for (int j = 0; j < 4; ++j) {
                    const int y = ylo + j, x = xlo + j;
                    wyv[j] = (y <= yhi) ? wyb[p*36 + y] * inv_area : 0.f;
                    wxv[j] = (x <= xhi) ? wxb[q*36 + x] : 0.f;
                }
                float ac0=0.f,ac1=0.f,ac2=0.f,ac3=0.f,ac4=0.f,ac5=0.f,ac6=0.f,ac7=0.f;
                #pragma unroll
                for (int yy = 0; yy < 4; ++yy) {
                    const int y = min(ylo + yy, 35);
                    const unsigned short* rowp = ft + (size_t)(y * 36) * 256 + ln * 8;
                    #pragma unroll
                    for (int xx = 0; xx < 4; ++xx) {
                        const int x = min(xlo + xx, 35);
                        const float wgt = wyv[yy] * wxv[xx];
                        const uint4 v = *(const uint4*)(rowp + x * 256);
                        ac0 = fmaf(wgt, b2f(v.x & 0xFFFFu), ac0);
                        ac1 = fmaf(wgt, b2f(v.x >> 16),     ac1);
                        ac2 = fmaf(wgt, b2f(v.y & 0xFFFFu), ac2);
                        ac3 = fmaf(wgt, b2f(v.y >> 16),     ac3);
                        ac4 = fmaf(wgt, b2f(v.z & 0xFFFFu), ac4);
                        ac5 = fmaf(wgt, b2f(v.z >> 16),     ac5);
                        ac6 = fmaf(wgt, b2f(v.w & 0xFFFFu), ac6);
                        ac7 = fmaf(wgt, b2f(v.w >> 16),     ac7);
                    }
                }
                *(uint4*)(smem + XS_OFF + rr*XS_RR + s * 512 + ((16 * ln) ^ SWZ(s))) =
                    make_uint4(pk2(ac0,ac1), pk2(ac2,ac3), pk2(ac4,ac5), pk2(ac6,ac7));
            }
        } else {
            const float* fb = feat + (size_t)bfr * CH * 36 * 36;
            for (int o = tid; o < CH * 49; o += NT) {
                int c = o / 49, s = o - c * 49;
                int p = s / 7, q = s - p * 7;
                float sy = y1 + bwy * p, sx = x1 + bwx * q;
                int ylo = max(0, (int)floorf(sy)), yhi = min(35, (int)ceilf(sy + bwy));
                int xlo = max(0, (int)floorf(sx)), xhi = min(35, (int)ceilf(sx + bwx));
                const float* fc = fb + c * 1296;
                float acc = 0.f;
                for (int y = ylo; y <= yhi; ++y) {
                    float wyv = wyb[p * 36 + y];
                    for (int x = xlo; x <= xhi; ++x)
                        acc = fmaf(wyv * wxb[q * 36 + x], fc[y * 36 + x], acc);
                }
                *(unsigned short*)(smem + XS_OFF + rr*XS_RR + s * 512 + ((2 * c) ^ SWZ(s))) =
                    bf16bits(acc * inv_area);
            }
        }
    }

    // wave geometry
    const int mt12 = w_ & 3, nt12 = w_ >> 2;           // conv1/2: 4m x 2n
    const int col12 = nt12 * 32 + ln;
    const int ncl12 = min(col12, 48);
    const int mg = w_ >> 1, ng = w_ & 1;               // conv3/deconv: (2 mt) x 2n
    const int col3 = ng * 32 + ln;
    const int ncl3 = min(col3, 48);

    // prefetch: first 4 A-frags of the upcoming phase, issued pre-barrier
    bh8 pf[4] = {};
    if (USE_WS) {
        #pragma unroll
        for (int t = 0; t < 4; ++t)
            pf[t] = ld_bh8(ws + A1OFF + ((((0*4 + mt12)*16 + t)*64 + lane) << 4));
    }
    BAR();

    // ---- Phase C: bottleneck blocks (A shared across both ROIs) ----
    #pragma unroll 1
    for (int ib = 0; ib < NB; ++ib) {
        // ===== conv1: xs(256) -> t1(128 interior), A loaded once, 2 acc =====
        {
            const unsigned char* bb0 = smem + XS_OFF + 0*XS_RR + ncl12 * 512;
            const unsigned char* bb1 = smem + XS_OFF + 1*XS_RR + ncl12 * 512;
            const int bswz = SWZ(ncl12);
            f16v acc0 = {}, acc1 = {};
            #pragma unroll
            for (int t = 0; t < 16; ++t) {
                bh8 a;
                if (USE_WS) a = (t < 4) ? pf[t]
                                        : ld_bh8(ws + A1OFF + ((((ib*4 + mt12)*16 + t)*64 + lane) << 4));
                else        a = cvt8(w1 + (size_t)(ib*BC + mt12*32 + ln)*CH + t*16 + 8*h);
                bh8 b0 = ld_bh8(bb0 + ((t*32 + cb) ^ bswz));
                bh8 b1 = ld_bh8(bb1 + ((t*32 + cb) ^ bswz));
                acc0 = __builtin_amdgcn_mfma_f32_32x32x16_bf16(a, b0, acc0, 0, 0, 0);
                acc1 = __builtin_amdgcn_mfma_f32_32x32x16_bf16(a, b1, acc1, 0, 0, 0);
            }
            if (col12 < 49) {
                const int row = (col12/7 + 1)*9 + (col12 - (col12/7)*7) + 1;
                epi_store(acc0, mt12*32, h, s1 + ib*BC, b1 + ib*BC,
                          smem + T1_OFF + 0*T1_RR + row*256, SWZ(row));
                epi_store(acc1, mt12*32, h, s1 + ib*BC, b1 + ib*BC,
                          smem + T1_OFF + 1*T1_RR + row*256, SWZ(row));
            }
        }
        if (USE_WS) {   // prefetch conv2 tap0 t=0..3
            #pragma unroll
            for (int t = 0; t < 4; ++t)
                pf[t] = ld_bh8(ws + A2OFF + (((((ib*9+0)*4 + mt12)*8 + t)*64 + lane) << 4));
        }
        BAR();

        // ===== conv2: 3x3 as 9 tap-GEMMs, A per tap loaded once, 2 acc =====
        {
            const int tr0 = (ncl12/7)*9 + (ncl12 - (ncl12/7)*7);
            f16v acc0 = {}, acc1 = {};
            #pragma unroll 1
            for (int ty = 0; ty < 3; ++ty) {
                #pragma unroll
                for (int tx = 0; tx < 3; ++tx) {
                    const int tap = ty*3 + tx;
                    bh8 aw[8];
                    #pragma unroll
                    for (int t = 0; t < 8; ++t) {
                        if (USE_WS) aw[t] = (ty == 0 && tx == 0 && t < 4) ? pf[t]
                                          : ld_bh8(ws + A2OFF + (((((ib*9+tap)*4 + mt12)*8 + t)*64 + lane) << 4));
                        else        aw[t] = gather8(w2 + ((size_t)(ib*BC + mt12*32 + ln)*BC + t*16 + 8*h)*9 + tap, 9);
                    }
                    const int row = tr0 + ty*9 + tx;
                    const unsigned char* bb0 = smem + T1_OFF + 0*T1_RR + row*256;
                    const unsigned char* bb1 = smem + T1_OFF + 1*T1_RR + row*256;
                    const int rs = SWZ(row);
                    #pragma unroll
                    for (int t = 0; t < 8; ++t) {
                        bh8 b0 = ld_bh8(bb0 + ((t*32 + cb) ^ rs));
                        bh8 b1 = ld_bh8(bb1 + ((t*32 + cb) ^ rs));
                        acc0 = __builtin_amdgcn_mfma_f32_32x32x16_bf16(aw[t], b0, acc0, 0, 0, 0);
                        acc1 = __builtin_amdgcn_mfma_f32_32x32x16_bf16(aw[t], b1, acc1, 0, 0, 0);
                    }
                }
            }
            if (col12 < 49) {
                epi_store(acc0, mt12*32, h, s2 + ib*BC, b2 + ib*BC,
                          smem + T2_OFF + 0*T2_RR + col12*256, SWZ(col12));
                epi_store(acc1, mt12*32, h, s2 + ib*BC, b2 + ib*BC,
                          smem + T2_OFF + 1*T2_RR + col12*256, SWZ(col12));
            }
        }
        if (USE_WS) {   // prefetch conv3 a0 t=0..3
            #pragma unroll
            for (int t = 0; t < 4; ++t)
                pf[t] = ld_bh8(ws + A3OFF + ((((ib*8 + 2*mg+0)*8 + t)*64 + lane) << 4));
        }
        BAR();

        // ===== conv3: t2(128) -> xs(256) + residual, A shared, 4 acc =====
        {
            const unsigned char* bb0 = smem + T2_OFF + 0*T2_RR + ncl3 * 256;
            const unsigned char* bb1 = smem + T2_OFF + 1*T2_RR + ncl3 * 256;
            const int bswz = SWZ(ncl3);
            f16v acc00 = {}, acc01 = {}, acc10 = {}, acc11 = {};   // [mtile][rr]
            #pragma unroll
            for (int t = 0; t < 8; ++t) {
                bh8 a0, a1;
                if (USE_WS) {
                    a0 = (t < 4) ? pf[t]
                                 : ld_bh8(ws + A3OFF + ((((ib*8 + 2*mg+0)*8 + t)*64 + lane) << 4));
                    a1 = ld_bh8(ws + A3OFF + ((((ib*8 + 2*mg+1)*8 + t)*64 + lane) << 4));
                } else {
                    a0 = cvt8(w3 + (size_t)(ib*CH + (2*mg+0)*32 + ln)*BC + t*16 + 8*h);
                    a1 = cvt8(w3 + (size_t)(ib*CH + (2*mg+1)*32 + ln)*BC + t*16 + 8*h);
                }
                bh8 b0 = ld_bh8(bb0 + ((t*32 + cb) ^ bswz));
                bh8 b1 = ld_bh8(bb1 + ((t*32 + cb) ^ bswz));
                acc00 = __builtin_amdgcn_mfma_f32_32x32x16_bf16(a0, b0, acc00, 0, 0, 0);
                acc01 = __builtin_amdgcn_mfma_f32_32x32x16_bf16(a0, b1, acc01, 0, 0, 0);
                acc10 = __builtin_amdgcn_mfma_f32_32x32x16_bf16(a1, b0, acc10, 0, 0, 0);
                acc11 = __builtin_amdgcn_mfma_f32_32x32x16_bf16(a1, b1, acc11, 0, 0, 0);
            }
            if (col3 < 49) {
                const int rs = SWZ(col3);
                unsigned char* rb0 = smem + XS_OFF + 0*XS_RR + col3*512;
                unsigned char* rb1 = smem + XS_OFF + 1*XS_RR + col3*512;
                epi_res(acc00, (2*mg+0)*32, h, s3 + ib*CH, b3 + ib*CH, rb0, rs);
                epi_res(acc10, (2*mg+1)*32, h, s3 + ib*CH, b3 + ib*CH, rb0, rs);
                epi_res(acc01, (2*mg+0)*32, h, s3 + ib*CH, b3 + ib*CH, rb1, rs);
                epi_res(acc11, (2*mg+1)*32, h, s3 + ib*CH, b3 + ib*CH, rb1, rs);
            }
        }
        if (USE_WS) {   // prefetch next conv1 (ib+1) or deconv quad0
            #pragma unroll
            for (int t = 0; t < 4; ++t) {
                if (ib < NB - 1)
                    pf[t] = ld_bh8(ws + A1OFF + (((((ib+1)*4 + mt12)*16 + t)*64 + lane) << 4));
                else
                    pf[t] = ld_bh8(ws + ATOFF + ((((0*8 + 2*mg+0)*16 + t)*64 + lane) << 4));
            }
        }
        BAR();
    }

    // ---- Phase D: deconv, 2 quads unrolled per pass (8 acc), A shared, fused head ----
    {
        const unsigned char* bb0 = smem + XS_OFF + 0*XS_RR + ncl3 * 512;
        const unsigned char* bb1 = smem + XS_OFF + 1*XS_RR + ncl3 * 512;
        const int bswz = SWZ(ncl3);
        #pragma unroll 1
        for (int qp = 0; qp < 2; ++qp) {
            const int qA = 2*qp, qB = 2*qp + 1;
            f16v aA00 = {}, aA01 = {}, aA10 = {}, aA11 = {};   // quad qA [mtile][rr]
            f16v aB00 = {}, aB01 = {}, aB10 = {}, aB11 = {};   // quad qB
            #pragma unroll
            for (int t = 0; t < 16; ++t) {
                bh8 b0 = ld_bh8(bb0 + ((t*32 + cb) ^ bswz));
                bh8 b1 = ld_bh8(bb1 + ((t*32 + cb) ^ bswz));
                bh8 wA0, wA1, wB0, wB1;
                if (USE_WS) {
                    wA0 = (qp == 0 && t < 4) ? pf[t]
                                 : ld_bh8(ws + ATOFF + ((((qA*8 + 2*mg+0)*16 + t)*64 + lane) << 4));
                    wA1 = ld_bh8(ws + ATOFF + ((((qA*8 + 2*mg+1)*16 + t)*64 + lane) << 4));
                    wB0 = ld_bh8(ws + ATOFF + ((((qB*8 + 2*mg+0)*16 + t)*64 + lane) << 4));
                    wB1 = ld_bh8(ws + ATOFF + ((((qB*8 + 2*mg+1)*16 + t)*64 + lane) << 4));
                } else {
                    wA0 = gather8(wt + (size_t)(t*16 + 8*h)*1024 + ((2*mg+0)*32 + ln)*4 + qA, 1024);
                    wA1 = gather8(wt + (size_t)(t*16 + 8*h)*1024 + ((2*mg+1)*32 + ln)*4 + qA, 1024);
                    wB0 = gather8(wt + (size_t)(t*16 + 8*h)*1024 + ((2*mg+0)*32 + ln)*4 + qB, 1024);
                    wB1 = gather8(wt + (size_t)(t*16 + 8*h)*1024 + ((2*mg+1)*32 + ln)*4 + qB, 1024);
                }
                aA00 = __builtin_amdgcn_mfma_f32_32x32x16_bf16(wA0, b0, aA00, 0, 0, 0);
                aA01 = __builtin_amdgcn_mfma_f32_32x32x16_bf16(wA0, b1, aA01, 0, 0, 0);
                aA10 = __builtin_amdgcn_mfma_f32_32x32x16_bf16(wA1, b0, aA10, 0, 0, 0);
                aA11 = __builtin_amdgcn_mfma_f32_32x32x16_bf16(wA1, b1, aA11, 0, 0, 0);
                aB00 = __builtin_amdgcn_mfma_f32_32x32x16_bf16(wB0, b0, aB00, 0, 0, 0);
                aB01 = __builtin_amdgcn_mfma_f32_32x32x16_bf16(wB0, b1, aB01, 0, 0, 0);
                aB10 = __builtin_amdgcn_mfma_f32_32x32x16_bf16(wB1, b0, aB10, 0, 0, 0);
                aB11 = __builtin_amdgcn_mfma_f32_32x32x16_bf16(wB1, b1, aB11, 0, 0, 0);
            }
            float pA0 = dq_part(aA00, (2*mg+0)*32, h, bt, wm)
                      + dq_part(aA10, (2*mg+1)*32, h, bt, wm);
            float pA1 = dq_part(aA01, (2*mg+0)*32, h, bt, wm)
                      + dq_part(aA11, (2*mg+1)*32, h, bt, wm);
            float pB0 = dq_part(aB00, (2*mg+0)*32, h, bt, wm)
                      + dq_part(aB10, (2*mg+1)*32, h, bt, wm);
            float pB1 = dq_part(aB01, (2*mg+0)*32, h, bt, wm)
                      + dq_part(aB11, (2*mg+1)*32, h, bt, wm);
            pA0 += __shfl_down(pA0, 32);
            pA1 += __shfl_down(pA1, 32);
            pB0 += __shfl_down(pB0, 32);
            pB1 += __shfl_down(pB1, 32);
            if (h == 0 && col3 < 49) {
                ((float*)(smem + LG_OFF + 0*4096))[(qA*4 + mg)*64 + col3] = pA0;
                ((float*)(smem + LG_OFF + 1*4096))[(qA*4 + mg)*64 + col3] = pA1;
                ((float*)(smem + LG_OFF + 0*4096))[(qB*4 + mg)*64 + col3] = pB0;
                ((float*)(smem + LG_OFF + 1*4096))[(qB*4 + mg)*64 + col3] = pB1;
            }
        }
    }
    BAR();

    // ---- final: sigmoid + scatter to 14x14 for both ROIs ----
    #pragma unroll
    for (int rr = 0; rr < 2; ++rr) {
        if (tid < 196) {
            const float* lg = (const float*)(smem + LG_OFF + rr*4096);
            const int quad = tid / 49, s = tid - quad*49;
            const float val = lg[(quad*4+0)*64 + s] + lg[(quad*4+1)*64 + s]
                            + lg[(quad*4+2)*64 + s] + lg[(quad*4+3)*64 + s] + bm[0];
            const int p = s / 7, q = s - p*7;
            const int dy = quad >> 1, dx = quad & 1;
            out[(size_t)(r0 + rr) * 196 + (2*p + dy)*14 + (2*q + dx)] =
                1.f / (1.f + expf(-val));
        }
    }
}

extern "C" void kernel_launch(void* const* d_in, const int* in_sizes, int n_in,
                              void* d_out, int out_size, void* d_ws, size_t ws_size,
                              hipStream_t stream) {
    const float* feat = (const float*)d_in[0];
    const float* bbox = (const float*)d_in[1];
    const float* w1   = (const float*)d_in[2];
    const float* s1   = (const float*)d_in[3];
    const float* b1   = (const float*)d_in[4];
    const float* w2   = (const float*)d_in[5];
    const float* s2   = (const float*)d_in[6];
    const float* b2   = (const float*)d_in[7];
    const float* w3   = (const float*)d_in[8];
    const float* s3   = (const float*)d_in[9];
    const float* b3   = (const float*)d_in[10];
    const float* wt   = (const float*)d_in[11];
    const float* bt   = (const float*)d_in[12];
    const float* wm   = (const float*)d_in[13];
    const float* bm   = (const float*)d_in[14];
    float* out = (float*)d_out;

    if (ws_size >= (size_t)WS_FULL) {
        unsigned char* ws = (unsigned char*)d_ws;
        hipLaunchKernelGGL(prep_all, dim3(1024), dim3(256), 0, stream,
                           feat, w1, w2, w3, wt, ws, 1);
        hipLaunchKernelGGL((masknet_mfma<1,1>), dim3(NROI/2), dim3(NT), 0, stream,
                           feat, bbox, w1, s1, b1, w2, s2, b2, w3, s3, b3,
                           wt, bt, wm, bm, ws, out);
    } else if (ws_size >= (size_t)WS_BYTES) {
        unsigned char* ws = (unsigned char*)d_ws;
        hipLaunchKernelGGL(prep_all, dim3(448), dim3(256), 0, stream,
                           feat, w1, w2, w3, wt, ws, 0);
        hipLaunchKernelGGL((masknet_mfma<1,0>), dim3(NROI/2), dim3(NT), 0, stream,
                           feat, bbox, w1, s1, b1, w2, s2, b2, w3, s3, b3,
                           wt, bt, wm, bm, ws, out);
    } else {
        hipLaunchKernelGGL((masknet_mfma<0,0>), dim3(NROI/2), dim3(NT), 0, stream,
                           feat, bbox, w1, s1, b1, w2, s2, b2, w3, s3, b3,
                           wt, bt, wm, bm, (const unsigned char*)nullptr, out);
    }
}